// Round 1
// baseline (232.815 us; speedup 1.0000x reference)
//
#include <hip/hip_runtime.h>
#include <stdint.h>

// Problem: B=8, L=2048, D=512, H=8, P=4, C=64.  M = B*L = 16384.
#define M_ROWS 16384

using short8  = __attribute__((ext_vector_type(8))) short;
using floatx4 = __attribute__((ext_vector_type(4))) float;

__device__ __forceinline__ unsigned short f2bf(float f) {
  union { float f; unsigned u; } v; v.f = f;
  unsigned r = v.u + 0x7fffu + ((v.u >> 16) & 1u);   // RNE
  return (unsigned short)(r >> 16);
}
__device__ __forceinline__ float bf2f(unsigned short u) {
  union { unsigned u; float f; } v; v.u = ((unsigned)u) << 16; return v.f;
}

__device__ __forceinline__ void load_lds16(const unsigned short* g, unsigned short* l) {
  __builtin_amdgcn_global_load_lds(
      (const __attribute__((address_space(1))) unsigned int*)g,
      (__attribute__((address_space(3))) unsigned int*)l, 16, 0, 0);
}

__device__ __forceinline__ void store_val(float* p, float v) { *p = v; }
__device__ __forceinline__ void store_val(unsigned short* p, float v) { *p = f2bf(v); }

// ---------------- conversion / packing kernels ----------------

__global__ __launch_bounds__(256) void conv_bf16(const float* __restrict__ src,
                                                 unsigned short* __restrict__ dst, int n4) {
  int i = blockIdx.x * 256 + threadIdx.x;
  if (i >= n4) return;
  float4 v = ((const float4*)src)[i];
  ushort4 o;
  o.x = f2bf(v.x); o.y = f2bf(v.y); o.z = f2bf(v.z); o.w = f2bf(v.w);
  ((ushort4*)dst)[i] = o;
}

// dst[n*512+k] = bf16(src[k*512+n])   (512x512 weight -> B^T bf16)
__global__ __launch_bounds__(256) void transpose_bf16(const float* __restrict__ src,
                                                      unsigned short* __restrict__ dst) {
  int idx = blockIdx.x * 256 + threadIdx.x;
  int n = idx >> 9, k = idx & 511;
  dst[idx] = f2bf(src[(k << 9) + n]);
}

// Wcat[k][0:64]=W_off[k][:], Wcat[k][64:96]=W_aw[k][:]; bcat likewise (fp32)
__global__ __launch_bounds__(256) void buildcat(const float* __restrict__ Woff,
                                                const float* __restrict__ Waw,
                                                const float* __restrict__ boff,
                                                const float* __restrict__ baw,
                                                float* __restrict__ Wcat,
                                                float* __restrict__ bcat) {
  int idx = blockIdx.x * 256 + threadIdx.x;   // k*96+n
  if (idx < 512 * 96) {
    int k = idx / 96, n = idx - k * 96;
    Wcat[idx] = (n < 64) ? Woff[(k << 6) + n] : Waw[(k << 5) + (n - 64)];
  }
  if (idx < 96) bcat[idx] = (idx < 64) ? boff[idx] : baw[idx - 64];
}

// ---------------- bf16 MFMA GEMM:  C[M][N] = A[M][K] * Bt[N][K]^T + bias ----------------
// m97 structure: 128x128 tile, BK=32, 4 waves as 2x2 of 64x64, 16x16x32 MFMA,
// global_load_lds width=16 (LDS layout is lane-ordered row-major [128][32], no padding).
template <typename OutT>
__global__ __launch_bounds__(256) void gemm_bt(const unsigned short* __restrict__ A,
                                               const unsigned short* __restrict__ Bt,
                                               const float* __restrict__ bias,
                                               OutT* __restrict__ C, int N, int K) {
  __shared__ __align__(16) unsigned short lA[128 * 32];
  __shared__ __align__(16) unsigned short lB[128 * 32];
  int tid  = threadIdx.x;
  int lane = tid & 63, wv = tid >> 6;
  int wm = wv & 1, wn = wv >> 1;
  int lrow = lane & 15, quad = lane >> 4;
  int rowBlk = blockIdx.y * 128, colBlk = blockIdx.x * 128;

  const unsigned short* Ab = A + (size_t)rowBlk * K;
  const unsigned short* Bb = Bt + (size_t)colBlk * K;
  int r0 = tid >> 2;            // 0..63
  int c0 = (tid & 3) << 3;      // 0,8,16,24

  floatx4 acc[4][4];
#pragma unroll
  for (int i = 0; i < 4; i++)
#pragma unroll
    for (int j = 0; j < 4; j++) acc[i][j] = (floatx4){0.f, 0.f, 0.f, 0.f};

  for (int k0 = 0; k0 < K; k0 += 32) {
    load_lds16(Ab + (size_t)r0 * K + k0 + c0,        lA + tid * 8);
    load_lds16(Ab + (size_t)(r0 + 64) * K + k0 + c0, lA + 2048 + tid * 8);
    load_lds16(Bb + (size_t)r0 * K + k0 + c0,        lB + tid * 8);
    load_lds16(Bb + (size_t)(r0 + 64) * K + k0 + c0, lB + 2048 + tid * 8);
    __syncthreads();   // compiler emits vmcnt(0) drain before barrier

    short8 a[4], b[4];
#pragma unroll
    for (int mi = 0; mi < 4; mi++)
      a[mi] = *(const short8*)&lA[(wm * 64 + mi * 16 + lrow) * 32 + quad * 8];
#pragma unroll
    for (int ni = 0; ni < 4; ni++)
      b[ni] = *(const short8*)&lB[(wn * 64 + ni * 16 + lrow) * 32 + quad * 8];
#pragma unroll
    for (int mi = 0; mi < 4; mi++)
#pragma unroll
      for (int ni = 0; ni < 4; ni++)
        acc[mi][ni] = __builtin_amdgcn_mfma_f32_16x16x32_bf16(a[mi], b[ni], acc[mi][ni], 0, 0, 0);
    __syncthreads();
  }

  // C/D layout: col = lane&15, row = quad*4 + reg   [verified m89/m91]
#pragma unroll
  for (int ni = 0; ni < 4; ni++) {
    int col = colBlk + wn * 64 + ni * 16 + lrow;
    float bv = bias[col];
#pragma unroll
    for (int mi = 0; mi < 4; mi++) {
      int row = rowBlk + wm * 64 + mi * 16 + quad * 4;
#pragma unroll
      for (int r = 0; r < 4; r++)
        store_val(&C[(size_t)(row + r) * N + col], acc[mi][ni][r] + bv);
    }
  }
}

// ---------------- fp32 off/aw projection: offaw[16384][96] = Q @ Wcat + bcat ----------------
// MUST be fp32: coordinate path multiplies offset error by 1024 (grid-sample),
// and adjacent v rows are i.i.d. -> bf16 here would blow past the 1e-2 threshold.
// grid (2, 256): x = k-half (split-K for occupancy), y = 64-row tile.
__global__ __launch_bounds__(256) void offaw_gemm(const float* __restrict__ Q,
                                                  const float* __restrict__ Wcat,
                                                  const float* __restrict__ bcat,
                                                  float* __restrict__ p0,
                                                  float* __restrict__ p1) {
  __shared__ float lA[64 * 16];
  __shared__ float lB[16 * 96];
  int tid = threadIdx.x;
  int khalf = blockIdx.x;
  int row0 = blockIdx.y * 64;
  int tx = tid & 15, ty = tid >> 4;
  int ar = tid >> 2, ac = (tid & 3) << 2;

  float acc[4][6];
#pragma unroll
  for (int i = 0; i < 4; i++)
#pragma unroll
    for (int j = 0; j < 6; j++) acc[i][j] = 0.f;

  int kbeg = khalf * 256;
  for (int k0 = kbeg; k0 < kbeg + 256; k0 += 16) {
    *(float4*)&lA[ar * 16 + ac] = *(const float4*)&Q[(size_t)(row0 + ar) * 512 + k0 + ac];
#pragma unroll
    for (int j = 0; j < 6; j++) {
      int e = tid + j * 256;                  // rows k0..k0+15 are contiguous in Wcat
      lB[e] = Wcat[(size_t)k0 * 96 + e];
    }
    __syncthreads();
#pragma unroll
    for (int kk = 0; kk < 16; kk++) {
      float a[4], b[6];
#pragma unroll
      for (int i = 0; i < 4; i++) a[i] = lA[(ty + (i << 4)) * 16 + kk];
#pragma unroll
      for (int j = 0; j < 6; j++) b[j] = lB[kk * 96 + tx + (j << 4)];
#pragma unroll
      for (int i = 0; i < 4; i++)
#pragma unroll
        for (int j = 0; j < 6; j++) acc[i][j] += a[i] * b[j];
    }
    __syncthreads();
  }

  float* outp = (khalf == 0) ? p0 : p1;
#pragma unroll
  for (int i = 0; i < 4; i++) {
    int r = row0 + ty + (i << 4);
#pragma unroll
    for (int j = 0; j < 6; j++) {
      int c = tx + (j << 4);
      float v = acc[i][j];
      if (khalf == 0) v += bcat[c];
      outp[(size_t)r * 96 + c] = v;
    }
  }
}

// ---------------- fused softmax + 1-D grid-sample gather ----------------
// One block per (b,l) row.  iy0 == 0 always (iy in [0,0.5]) so ywt = 1 - 0.5*loc_y.
// i0 in [1023,2047] always valid; i1 masked when == 2048.
__global__ __launch_bounds__(256) void sample_kernel(const float* __restrict__ p0,
                                                     const float* __restrict__ p1,
                                                     const unsigned short* __restrict__ v,
                                                     unsigned short* __restrict__ attn) {
  int row = blockIdx.x;
  int b = row >> 11, l = row & 2047;
  __shared__ float s_w0[32], s_w1[32];
  __shared__ int s_i0[32], s_i1[32];
  int tid = threadIdx.x;

  if (tid < 32) {                 // one thread per (h,p)
    int base = row * 96;
    float lg = p0[base + 64 + tid] + p1[base + 64 + tid];
    float mx = fmaxf(lg, __shfl_xor(lg, 1));
    mx = fmaxf(mx, __shfl_xor(mx, 2));
    float e = __expf(lg - mx);
    float s = e + __shfl_xor(e, 1);
    s = s + __shfl_xor(s, 2);
    float aw = e / s;

    float ox = p0[base + 2 * tid] + p1[base + 2 * tid];
    float oy = p0[base + 2 * tid + 1] + p1[base + 2 * tid + 1];
    float refy = (float)l * (1.0f / 2047.0f);
    float lx = fminf(fmaxf(ox, 0.0f), 1.0f);
    float ly = fminf(fmaxf(oy + refy, 0.0f), 1.0f);
    float ix = ((lx + 1.0f) * 2048.0f - 1.0f) * 0.5f;
    float ywt = 1.0f - ly * 0.5f;
    float ix0 = floorf(ix);
    float fx = ix - ix0;
    int i0 = (int)ix0;
    int i1 = i0 + 1;
    s_w0[tid] = aw * ywt * (1.0f - fx);
    s_w1[tid] = (i1 < 2048) ? (aw * ywt * fx) : 0.0f;
    s_i0[tid] = i0;
    s_i1[tid] = (i1 < 2048) ? i1 : 2047;
  }
  __syncthreads();

  const unsigned short* vb = v + ((size_t)(b << 11)) * 512;
  int c = tid & 63;
#pragma unroll
  for (int hh = 0; hh < 2; hh++) {
    int h = (tid >> 6) + (hh << 2);          // wave-uniform head
    const unsigned short* vhc = vb + h * 64 + c;
    float acc = 0.0f;
#pragma unroll
    for (int p = 0; p < 4; p++) {
      int t = (h << 2) + p;
      acc += s_w0[t] * bf2f(vhc[(size_t)s_i0[t] << 9]) +
             s_w1[t] * bf2f(vhc[(size_t)s_i1[t] << 9]);
    }
    attn[(size_t)row * 512 + h * 64 + c] = f2bf(acc);
  }
}

// ---------------- host launcher ----------------
extern "C" void kernel_launch(void* const* d_in, const int* in_sizes, int n_in,
                              void* d_out, int out_size, void* d_ws, size_t ws_size,
                              hipStream_t stream) {
  (void)in_sizes; (void)n_in; (void)out_size; (void)ws_size;
  const float* query = (const float*)d_in[0];
  // d_in[1] = key_in : unused by the reference
  const float* value = (const float*)d_in[2];
  const float* W_v   = (const float*)d_in[3];
  const float* b_v   = (const float*)d_in[4];
  const float* W_off = (const float*)d_in[5];
  const float* b_off = (const float*)d_in[6];
  const float* W_aw  = (const float*)d_in[7];
  const float* b_aw  = (const float*)d_in[8];
  const float* W_out = (const float*)d_in[9];
  const float* b_out = (const float*)d_in[10];
  float* out = (float*)d_out;

  char* ws = (char*)d_ws;
  const size_t MB = 1ull << 20;
  unsigned short* val_bf = (unsigned short*)(ws);                  // 16 MB (value bf16)
  unsigned short* attn   = val_bf;                                 // aliases: value dead after gemm1
  unsigned short* v_bf   = (unsigned short*)(ws + 16 * MB);        // 16 MB (v projection, bf16)
  float* offp0           = (float*)(ws + 32 * MB);                 // 6 MB (off/aw k-half 0)
  float* offp1           = (float*)(ws + 38 * MB);                 // 6 MB (off/aw k-half 1)
  unsigned short* Wv_t   = (unsigned short*)(ws + 44 * MB);        // 0.5 MB
  unsigned short* Wo_t   = (unsigned short*)(ws + 44 * MB + 524288);
  float* Wcat            = (float*)(ws + 45 * MB);                 // 192 KB fp32
  float* bcat            = (float*)(ws + 45 * MB + 196608);

  conv_bf16<<<8192, 256, 0, stream>>>(value, val_bf, 2097152);
  transpose_bf16<<<1024, 256, 0, stream>>>(W_v, Wv_t);
  transpose_bf16<<<1024, 256, 0, stream>>>(W_out, Wo_t);
  buildcat<<<192, 256, 0, stream>>>(W_off, W_aw, b_off, b_aw, Wcat, bcat);

  // v = value @ W_v + b_v   (bf16 out)
  gemm_bt<unsigned short><<<dim3(4, 128), 256, 0, stream>>>(val_bf, Wv_t, b_v, v_bf, 512, 512);
  // off/aw = query @ [W_off|W_aw] + [b_off|b_aw]   (fp32, split-K)
  offaw_gemm<<<dim3(2, 256), 256, 0, stream>>>(query, Wcat, bcat, offp0, offp1);
  // softmax + grid-sample gather -> attn (bf16)
  sample_kernel<<<16384, 256, 0, stream>>>(offp0, offp1, v_bf, attn);
  // out = attn @ W_out + b_out   (fp32 out)
  gemm_bt<float><<<dim3(4, 128), 256, 0, stream>>>(attn, Wo_t, b_out, out, 512, 512);
}

// Round 2
// 231.080 us; speedup vs baseline: 1.0075x; 1.0075x over previous
//
#include <hip/hip_runtime.h>
#include <stdint.h>

// Problem: B=8, L=2048, D=512, H=8, P=4, C=64.  M = B*L = 16384.
#define M_ROWS 16384
#define PSZF (16384 * 96)   // elements per offaw partial buffer

using short8  = __attribute__((ext_vector_type(8))) short;
using floatx4 = __attribute__((ext_vector_type(4))) float;

__device__ __forceinline__ unsigned short f2bf(float f) {
  union { float f; unsigned u; } v; v.f = f;
  unsigned r = v.u + 0x7fffu + ((v.u >> 16) & 1u);   // RNE
  return (unsigned short)(r >> 16);
}
__device__ __forceinline__ float bf2f(unsigned short u) {
  union { unsigned u; float f; } v; v.u = ((unsigned)u) << 16; return v.f;
}

__device__ __forceinline__ void load_lds16(const unsigned short* g, unsigned short* l) {
  __builtin_amdgcn_global_load_lds(
      (const __attribute__((address_space(1))) unsigned int*)g,
      (__attribute__((address_space(3))) unsigned int*)l, 16, 0, 0);
}

__device__ __forceinline__ void store_val(float* p, float v) { *p = v; }
__device__ __forceinline__ void store_val(unsigned short* p, float v) { *p = f2bf(v); }

// ---------------- conversion / packing kernels ----------------

__global__ __launch_bounds__(256) void conv_bf16(const float* __restrict__ src,
                                                 unsigned short* __restrict__ dst, int n4) {
  int i = blockIdx.x * 256 + threadIdx.x;
  if (i >= n4) return;
  float4 v = ((const float4*)src)[i];
  ushort4 o;
  o.x = f2bf(v.x); o.y = f2bf(v.y); o.z = f2bf(v.z); o.w = f2bf(v.w);
  ((ushort4*)dst)[i] = o;
}

// dst[n*512+k] = bf16(src[k*512+n])   (512x512 weight -> B^T bf16)
__global__ __launch_bounds__(256) void transpose_bf16(const float* __restrict__ src,
                                                      unsigned short* __restrict__ dst) {
  int idx = blockIdx.x * 256 + threadIdx.x;
  int n = idx >> 9, k = idx & 511;
  dst[idx] = f2bf(src[(k << 9) + n]);
}

// Bt layout [96][512]: rows 0..63 = W_off columns, rows 64..95 = W_aw columns.
// hi = bf16(w), lo = bf16(w - hi)  (split-bf16 for near-fp32 MFMA GEMM)
__global__ __launch_bounds__(256) void buildcat(const float* __restrict__ Woff,
                                                const float* __restrict__ Waw,
                                                const float* __restrict__ boff,
                                                const float* __restrict__ baw,
                                                unsigned short* __restrict__ Bhi,
                                                unsigned short* __restrict__ Blo,
                                                float* __restrict__ bcat) {
  int idx = blockIdx.x * 256 + threadIdx.x;   // n*512 + k, n<96
  if (idx < 96 * 512) {
    int n = idx >> 9, k = idx & 511;
    float w = (n < 64) ? Woff[(k << 6) + n] : Waw[(k << 5) + (n - 64)];
    unsigned short hi = f2bf(w);
    Bhi[idx] = hi;
    Blo[idx] = f2bf(w - bf2f(hi));
  }
  if (idx < 96) bcat[idx] = (idx < 64) ? boff[idx] : baw[idx - 64];
}

// ---------------- bf16 MFMA GEMM:  C[M][N] = A[M][K] * Bt[N][K]^T + bias ----------------
// m97 structure: 128x128 tile, BK=32, 4 waves as 2x2 of 64x64, 16x16x32 MFMA,
// global_load_lds width=16 (LDS layout is lane-ordered row-major [128][32], no padding).
template <typename OutT>
__global__ __launch_bounds__(256) void gemm_bt(const unsigned short* __restrict__ A,
                                               const unsigned short* __restrict__ Bt,
                                               const float* __restrict__ bias,
                                               OutT* __restrict__ C, int N, int K) {
  __shared__ __align__(16) unsigned short lA[128 * 32];
  __shared__ __align__(16) unsigned short lB[128 * 32];
  int tid  = threadIdx.x;
  int lane = tid & 63, wv = tid >> 6;
  int wm = wv & 1, wn = wv >> 1;
  int lrow = lane & 15, quad = lane >> 4;
  int rowBlk = blockIdx.y * 128, colBlk = blockIdx.x * 128;

  const unsigned short* Ab = A + (size_t)rowBlk * K;
  const unsigned short* Bb = Bt + (size_t)colBlk * K;
  int r0 = tid >> 2;            // 0..63
  int c0 = (tid & 3) << 3;      // 0,8,16,24

  floatx4 acc[4][4];
#pragma unroll
  for (int i = 0; i < 4; i++)
#pragma unroll
    for (int j = 0; j < 4; j++) acc[i][j] = (floatx4){0.f, 0.f, 0.f, 0.f};

  for (int k0 = 0; k0 < K; k0 += 32) {
    load_lds16(Ab + (size_t)r0 * K + k0 + c0,        lA + tid * 8);
    load_lds16(Ab + (size_t)(r0 + 64) * K + k0 + c0, lA + 2048 + tid * 8);
    load_lds16(Bb + (size_t)r0 * K + k0 + c0,        lB + tid * 8);
    load_lds16(Bb + (size_t)(r0 + 64) * K + k0 + c0, lB + 2048 + tid * 8);
    __syncthreads();

    short8 a[4], b[4];
#pragma unroll
    for (int mi = 0; mi < 4; mi++)
      a[mi] = *(const short8*)&lA[(wm * 64 + mi * 16 + lrow) * 32 + quad * 8];
#pragma unroll
    for (int ni = 0; ni < 4; ni++)
      b[ni] = *(const short8*)&lB[(wn * 64 + ni * 16 + lrow) * 32 + quad * 8];
#pragma unroll
    for (int mi = 0; mi < 4; mi++)
#pragma unroll
      for (int ni = 0; ni < 4; ni++)
        acc[mi][ni] = __builtin_amdgcn_mfma_f32_16x16x32_bf16(a[mi], b[ni], acc[mi][ni], 0, 0, 0);
    __syncthreads();
  }

  // C/D layout: col = lane&15, row = quad*4 + reg   [verified m89/m91]
#pragma unroll
  for (int ni = 0; ni < 4; ni++) {
    int col = colBlk + wn * 64 + ni * 16 + lrow;
    float bv = bias[col];
#pragma unroll
    for (int mi = 0; mi < 4; mi++) {
      int row = rowBlk + wm * 64 + mi * 16 + quad * 4;
#pragma unroll
      for (int r = 0; r < 4; r++)
        store_val(&C[(size_t)(row + r) * N + col], acc[mi][ni][r] + bv);
    }
  }
}

// ---------------- off/aw projection via split-bf16 MFMA ----------------
// offaw = Q@Wcat exactly needs ~fp32 precision on the offset columns (coordinate
// path amplifies error by 1024x).  Split: Q@W = Qhi@Whi + Qhi@Wlo + Qlo@Whi,
// residual Qlo@Wlo ~ 3e-7 -> negligible.  Segment s = blockIdx.x picks the
// (A-variant, B-variant) pair; A is read fp32 and split in-register during LDS
// staging (no materialized Qhi/Qlo).  64x96 tile, 2 waves (64x48 each), K=512.
__global__ __launch_bounds__(128) void offaw_mfma(const float* __restrict__ Q,
                                                  const unsigned short* __restrict__ Bhi,
                                                  const unsigned short* __restrict__ Blo,
                                                  const float* __restrict__ bcat,
                                                  float* __restrict__ P) {
  __shared__ __align__(16) unsigned short lA[64 * 32];
  __shared__ __align__(16) unsigned short lB[96 * 32];
  int seg = blockIdx.x;              // 0: hi@hi(+bias)  1: hi@lo  2: lo@hi
  int row0 = blockIdx.y * 64;
  int tid = threadIdx.x;             // 0..127
  int lane = tid & 63, wn = tid >> 6;
  int lrow = lane & 15, quad = lane >> 4;
  const unsigned short* Bt = (seg == 1) ? Blo : Bhi;
  bool wantlo = (seg == 2);
  float* out = P + (size_t)seg * PSZF;

  int ar = tid >> 1;                 // A-stage row 0..63
  int ach = (tid & 1) << 4;          // A-stage col base 0/16

  floatx4 acc[4][3];
#pragma unroll
  for (int i = 0; i < 4; i++)
#pragma unroll
    for (int j = 0; j < 3; j++) acc[i][j] = (floatx4){0.f, 0.f, 0.f, 0.f};

  const float* qrow = Q + (size_t)(row0 + ar) * 512 + ach;

  for (int k0 = 0; k0 < 512; k0 += 32) {
    // stage A: read fp32, split to hi or lo bf16 in-register, write LDS
#pragma unroll
    for (int j = 0; j < 4; j++) {
      float4 v = *(const float4*)(qrow + k0 + j * 4);
      if (wantlo) {
        v.x -= bf2f(f2bf(v.x)); v.y -= bf2f(f2bf(v.y));
        v.z -= bf2f(f2bf(v.z)); v.w -= bf2f(f2bf(v.w));
      }
      ushort4 o;
      o.x = f2bf(v.x); o.y = f2bf(v.y); o.z = f2bf(v.z); o.w = f2bf(v.w);
      *(ushort4*)&lA[ar * 32 + ach + j * 4] = o;
    }
    // stage B: 96x32 bf16 via global_load_lds (wave-uniform base + lane*16)
#pragma unroll
    for (int j = 0; j < 3; j++) {
      int e = tid + j * 128;                   // 0..383
      int n = e >> 2, c = (e & 3) << 3;
      load_lds16(Bt + (size_t)n * 512 + k0 + c, lB + e * 8);
    }
    __syncthreads();

    short8 a[4], b[3];
#pragma unroll
    for (int mi = 0; mi < 4; mi++)
      a[mi] = *(const short8*)&lA[(mi * 16 + lrow) * 32 + quad * 8];
#pragma unroll
    for (int ni = 0; ni < 3; ni++)
      b[ni] = *(const short8*)&lB[(wn * 48 + ni * 16 + lrow) * 32 + quad * 8];
#pragma unroll
    for (int mi = 0; mi < 4; mi++)
#pragma unroll
      for (int ni = 0; ni < 3; ni++)
        acc[mi][ni] = __builtin_amdgcn_mfma_f32_16x16x32_bf16(a[mi], b[ni], acc[mi][ni], 0, 0, 0);
    __syncthreads();
  }

#pragma unroll
  for (int ni = 0; ni < 3; ni++) {
    int col = wn * 48 + ni * 16 + lrow;
    float bv = (seg == 0) ? bcat[col] : 0.0f;
#pragma unroll
    for (int mi = 0; mi < 4; mi++) {
      int row = row0 + mi * 16 + quad * 4;
#pragma unroll
      for (int r = 0; r < 4; r++)
        out[(size_t)(row + r) * 96 + col] = acc[mi][ni][r] + bv;
    }
  }
}

// ---------------- fused softmax + 1-D grid-sample gather ----------------
// One block per (b,l) row.  iy0 == 0 always (iy in [0,0.5]) so ywt = 1 - 0.5*loc_y.
// i0 in [1023,2047] always valid; i1 masked when == 2048.
__global__ __launch_bounds__(256) void sample_kernel(const float* __restrict__ P,
                                                     const unsigned short* __restrict__ v,
                                                     unsigned short* __restrict__ attn) {
  int row = blockIdx.x;
  int b = row >> 11, l = row & 2047;
  __shared__ float s_w0[32], s_w1[32];
  __shared__ int s_i0[32], s_i1[32];
  int tid = threadIdx.x;

  if (tid < 32) {                 // one thread per (h,p)
    int base = row * 96;
    float lg = P[base + 64 + tid] + P[PSZF + base + 64 + tid] + P[2 * PSZF + base + 64 + tid];
    float mx = fmaxf(lg, __shfl_xor(lg, 1));
    mx = fmaxf(mx, __shfl_xor(mx, 2));
    float e = __expf(lg - mx);
    float s = e + __shfl_xor(e, 1);
    s = s + __shfl_xor(s, 2);
    float aw = e / s;

    float ox = P[base + 2 * tid] + P[PSZF + base + 2 * tid] + P[2 * PSZF + base + 2 * tid];
    float oy = P[base + 2 * tid + 1] + P[PSZF + base + 2 * tid + 1] + P[2 * PSZF + base + 2 * tid + 1];
    float refy = (float)l * (1.0f / 2047.0f);
    float lx = fminf(fmaxf(ox, 0.0f), 1.0f);
    float ly = fminf(fmaxf(oy + refy, 0.0f), 1.0f);
    float ix = ((lx + 1.0f) * 2048.0f - 1.0f) * 0.5f;
    float ywt = 1.0f - ly * 0.5f;
    float ix0 = floorf(ix);
    float fx = ix - ix0;
    int i0 = (int)ix0;
    int i1 = i0 + 1;
    s_w0[tid] = aw * ywt * (1.0f - fx);
    s_w1[tid] = (i1 < 2048) ? (aw * ywt * fx) : 0.0f;
    s_i0[tid] = i0;
    s_i1[tid] = (i1 < 2048) ? i1 : 2047;
  }
  __syncthreads();

  const unsigned short* vb = v + ((size_t)(b << 11)) * 512;
  int c = tid & 63;
#pragma unroll
  for (int hh = 0; hh < 2; hh++) {
    int h = (tid >> 6) + (hh << 2);          // wave-uniform head
    const unsigned short* vhc = vb + h * 64 + c;
    float acc = 0.0f;
#pragma unroll
    for (int p = 0; p < 4; p++) {
      int t = (h << 2) + p;
      acc += s_w0[t] * bf2f(vhc[(size_t)s_i0[t] << 9]) +
             s_w1[t] * bf2f(vhc[(size_t)s_i1[t] << 9]);
    }
    attn[(size_t)row * 512 + h * 64 + c] = f2bf(acc);
  }
}

// ---------------- host launcher ----------------
extern "C" void kernel_launch(void* const* d_in, const int* in_sizes, int n_in,
                              void* d_out, int out_size, void* d_ws, size_t ws_size,
                              hipStream_t stream) {
  (void)in_sizes; (void)n_in; (void)out_size; (void)ws_size;
  const float* query = (const float*)d_in[0];
  // d_in[1] = key_in : unused by the reference
  const float* value = (const float*)d_in[2];
  const float* W_v   = (const float*)d_in[3];
  const float* b_v   = (const float*)d_in[4];
  const float* W_off = (const float*)d_in[5];
  const float* b_off = (const float*)d_in[6];
  const float* W_aw  = (const float*)d_in[7];
  const float* b_aw  = (const float*)d_in[8];
  const float* W_out = (const float*)d_in[9];
  const float* b_out = (const float*)d_in[10];
  float* out = (float*)d_out;

  char* ws = (char*)d_ws;
  const size_t MB = 1ull << 20;
  unsigned short* val_bf = (unsigned short*)(ws);                  // 16 MB (value bf16)
  unsigned short* attn   = val_bf;                                 // aliases: value dead after gemm1
  unsigned short* v_bf   = (unsigned short*)(ws + 16 * MB);        // 16 MB (v projection, bf16)
  float* offP            = (float*)(ws + 32 * MB);                 // 3 x 6 MB offaw partials
  unsigned short* Wv_t   = (unsigned short*)(ws + 50 * MB);        // 0.5 MB
  unsigned short* Wo_t   = (unsigned short*)(ws + 50 * MB + 524288);
  unsigned short* Bhi    = (unsigned short*)(ws + 51 * MB);        // 96 KB
  unsigned short* Blo    = (unsigned short*)(ws + 51 * MB + 98304);
  float* bcat            = (float*)(ws + 51 * MB + 196608);

  conv_bf16<<<8192, 256, 0, stream>>>(value, val_bf, 2097152);
  transpose_bf16<<<1024, 256, 0, stream>>>(W_v, Wv_t);
  transpose_bf16<<<1024, 256, 0, stream>>>(W_out, Wo_t);
  buildcat<<<192, 256, 0, stream>>>(W_off, W_aw, b_off, b_aw, Bhi, Blo, bcat);

  // v = value @ W_v + b_v   (bf16 out)
  gemm_bt<unsigned short><<<dim3(4, 128), 256, 0, stream>>>(val_bf, Wv_t, b_v, v_bf, 512, 512);
  // off/aw = query @ [W_off|W_aw] via split-bf16 MFMA (3 segments -> 3 fp32 partials)
  offaw_mfma<<<dim3(3, 256), 128, 0, stream>>>(query, Bhi, Blo, bcat, offP);
  // softmax + grid-sample gather -> attn (bf16)
  sample_kernel<<<16384, 256, 0, stream>>>(offP, v_bf, attn);
  // out = attn @ W_out + b_out   (fp32 out)
  gemm_bt<float><<<dim3(4, 128), 256, 0, stream>>>(attn, Wo_t, b_out, out, 512, 512);
}

// Round 3
// 217.936 us; speedup vs baseline: 1.0683x; 1.0603x over previous
//
#include <hip/hip_runtime.h>
#include <stdint.h>

// Problem: B=8, L=2048, D=512, H=8, P=4, C=64.  M = B*L = 16384.
#define M_ROWS 16384
#define PSZF (16384 * 96)   // elements per offaw partial buffer (split-K half)

using short8  = __attribute__((ext_vector_type(8))) short;
using floatx4 = __attribute__((ext_vector_type(4))) float;

__device__ __forceinline__ unsigned short f2bf(float f) {
  union { float f; unsigned u; } v; v.f = f;
  unsigned r = v.u + 0x7fffu + ((v.u >> 16) & 1u);   // RNE
  return (unsigned short)(r >> 16);
}
__device__ __forceinline__ float bf2f(unsigned short u) {
  union { unsigned u; float f; } v; v.u = ((unsigned)u) << 16; return v.f;
}

__device__ __forceinline__ void load_lds16(const unsigned short* g, unsigned short* l) {
  __builtin_amdgcn_global_load_lds(
      (const __attribute__((address_space(1))) unsigned int*)g,
      (__attribute__((address_space(3))) unsigned int*)l, 16, 0, 0);
}

__device__ __forceinline__ void store_val(float* p, float v) { *p = v; }
__device__ __forceinline__ void store_val(unsigned short* p, float v) { *p = f2bf(v); }

// ---------------- fused conversion pass (memory-bound; VALU hides under HBM) ----
// blocks [0, 8192)   : value -> bf16
// blocks [8192,16384): query -> (Qhi, Qlo) split-bf16
__global__ __launch_bounds__(256) void conv_all(const float* __restrict__ value,
                                                const float* __restrict__ query,
                                                unsigned short* __restrict__ val_bf,
                                                unsigned short* __restrict__ Qhi,
                                                unsigned short* __restrict__ Qlo) {
  int i = blockIdx.x * 256 + threadIdx.x;
  if (i < 2097152) {
    float4 v = ((const float4*)value)[i];
    ushort4 o;
    o.x = f2bf(v.x); o.y = f2bf(v.y); o.z = f2bf(v.z); o.w = f2bf(v.w);
    ((ushort4*)val_bf)[i] = o;
  } else {
    int j = i - 2097152;
    float4 v = ((const float4*)query)[j];
    ushort4 hi, lo;
    hi.x = f2bf(v.x); hi.y = f2bf(v.y); hi.z = f2bf(v.z); hi.w = f2bf(v.w);
    lo.x = f2bf(v.x - bf2f(hi.x)); lo.y = f2bf(v.y - bf2f(hi.y));
    lo.z = f2bf(v.z - bf2f(hi.z)); lo.w = f2bf(v.w - bf2f(hi.w));
    ((ushort4*)Qhi)[j] = hi;
    ((ushort4*)Qlo)[j] = lo;
  }
}

// ---------------- fused weight prep ----------------
// [0,256K): W_v^T bf16   [256K,512K): W_out^T bf16
// [512K,512K+48K): Bhi/Blo = split-bf16 of [W_off|W_aw]^T  (layout [96][512])
// tail 96: bcat
__global__ __launch_bounds__(256) void prep_w(const float* __restrict__ W_v,
                                              const float* __restrict__ W_out,
                                              const float* __restrict__ Woff,
                                              const float* __restrict__ Waw,
                                              const float* __restrict__ boff,
                                              const float* __restrict__ baw,
                                              unsigned short* __restrict__ Wv_t,
                                              unsigned short* __restrict__ Wo_t,
                                              unsigned short* __restrict__ Bhi,
                                              unsigned short* __restrict__ Blo,
                                              float* __restrict__ bcat) {
  int idx = blockIdx.x * 256 + threadIdx.x;
  if (idx < 262144) {
    int n = idx >> 9, k = idx & 511;
    Wv_t[idx] = f2bf(W_v[(k << 9) + n]);
  } else if (idx < 524288) {
    int t = idx - 262144;
    int n = t >> 9, k = t & 511;
    Wo_t[t] = f2bf(W_out[(k << 9) + n]);
  } else if (idx < 524288 + 49152) {
    int t = idx - 524288;
    int n = t >> 9, k = t & 511;
    float w = (n < 64) ? Woff[(k << 6) + n] : Waw[(k << 5) + (n - 64)];
    unsigned short hi = f2bf(w);
    Bhi[t] = hi;
    Blo[t] = f2bf(w - bf2f(hi));
  } else if (idx < 524288 + 49152 + 96) {
    int t = idx - 524288 - 49152;
    bcat[t] = (t < 64) ? boff[t] : baw[t - 64];
  }
}

// ---------------- bf16 MFMA GEMM:  C[M][N] = A[M][K] * Bt[N][K]^T + bias ----------------
// m97 structure: 128x128 tile, BK=32, 4 waves as 2x2 of 64x64, 16x16x32 MFMA,
// global_load_lds width=16 (LDS layout is lane-ordered row-major [128][32], no padding).
template <typename OutT>
__global__ __launch_bounds__(256) void gemm_bt(const unsigned short* __restrict__ A,
                                               const unsigned short* __restrict__ Bt,
                                               const float* __restrict__ bias,
                                               OutT* __restrict__ C, int N, int K) {
  __shared__ __align__(16) unsigned short lA[128 * 32];
  __shared__ __align__(16) unsigned short lB[128 * 32];
  int tid  = threadIdx.x;
  int lane = tid & 63, wv = tid >> 6;
  int wm = wv & 1, wn = wv >> 1;
  int lrow = lane & 15, quad = lane >> 4;
  int rowBlk = blockIdx.y * 128, colBlk = blockIdx.x * 128;

  const unsigned short* Ab = A + (size_t)rowBlk * K;
  const unsigned short* Bb = Bt + (size_t)colBlk * K;
  int r0 = tid >> 2;            // 0..63
  int c0 = (tid & 3) << 3;      // 0,8,16,24

  floatx4 acc[4][4];
#pragma unroll
  for (int i = 0; i < 4; i++)
#pragma unroll
    for (int j = 0; j < 4; j++) acc[i][j] = (floatx4){0.f, 0.f, 0.f, 0.f};

  for (int k0 = 0; k0 < K; k0 += 32) {
    load_lds16(Ab + (size_t)r0 * K + k0 + c0,        lA + tid * 8);
    load_lds16(Ab + (size_t)(r0 + 64) * K + k0 + c0, lA + 2048 + tid * 8);
    load_lds16(Bb + (size_t)r0 * K + k0 + c0,        lB + tid * 8);
    load_lds16(Bb + (size_t)(r0 + 64) * K + k0 + c0, lB + 2048 + tid * 8);
    __syncthreads();

    short8 a[4], b[4];
#pragma unroll
    for (int mi = 0; mi < 4; mi++)
      a[mi] = *(const short8*)&lA[(wm * 64 + mi * 16 + lrow) * 32 + quad * 8];
#pragma unroll
    for (int ni = 0; ni < 4; ni++)
      b[ni] = *(const short8*)&lB[(wn * 64 + ni * 16 + lrow) * 32 + quad * 8];
#pragma unroll
    for (int mi = 0; mi < 4; mi++)
#pragma unroll
      for (int ni = 0; ni < 4; ni++)
        acc[mi][ni] = __builtin_amdgcn_mfma_f32_16x16x32_bf16(a[mi], b[ni], acc[mi][ni], 0, 0, 0);
    __syncthreads();
  }

  // C/D layout: col = lane&15, row = quad*4 + reg   [verified m89/m91]
#pragma unroll
  for (int ni = 0; ni < 4; ni++) {
    int col = colBlk + wn * 64 + ni * 16 + lrow;
    float bv = bias[col];
#pragma unroll
    for (int mi = 0; mi < 4; mi++) {
      int row = rowBlk + wm * 64 + mi * 16 + quad * 4;
#pragma unroll
      for (int r = 0; r < 4; r++)
        store_val(&C[(size_t)(row + r) * N + col], acc[mi][ni][r] + bv);
    }
  }
}

// ---------------- off/aw projection: pure-MFMA split-bf16 GEMM ----------------
// P[khalf] += Qhi@Bhi + Qhi@Blo + Qlo@Bhi over the khalf's 256 K (one accumulator).
// 64x96 tile, 4 waves as 2x2 of 32x48, all staging via global_load_lds (no VALU).
// grid (2, 256): x = khalf (split-K for 2 blocks/CU), y = 64-row tile.
__global__ __launch_bounds__(256) void offaw2(const unsigned short* __restrict__ Qhi,
                                              const unsigned short* __restrict__ Qlo,
                                              const unsigned short* __restrict__ Bhi,
                                              const unsigned short* __restrict__ Blo,
                                              const float* __restrict__ bcat,
                                              float* __restrict__ P) {
  __shared__ __align__(16) unsigned short lAhi[64 * 32];
  __shared__ __align__(16) unsigned short lAlo[64 * 32];
  __shared__ __align__(16) unsigned short lBhi[96 * 32];
  __shared__ __align__(16) unsigned short lBlo[96 * 32];
  int khalf = blockIdx.x;
  int row0 = blockIdx.y * 64;
  int tid = threadIdx.x;
  int lane = tid & 63, wv = tid >> 6;
  int wm = wv & 1, wn = wv >> 1;
  int lrow = lane & 15, quad = lane >> 4;
  int kbase = khalf << 8;

  int an = tid >> 2, ac = (tid & 3) << 3;          // A stage: row 0..63, col {0,8,16,24}
  const unsigned short* qhb = Qhi + (size_t)(row0 + an) * 512 + kbase + ac;
  const unsigned short* qlb = Qlo + (size_t)(row0 + an) * 512 + kbase + ac;
  int bn = tid >> 2, bc = (tid & 3) << 3;          // B stage part 1 (e = tid)
  int e2 = 256 + tid;                              // B stage part 2 (waves 0,1 only)
  int bn2 = e2 >> 2, bc2 = (e2 & 3) << 3;

  floatx4 acc[2][3];
#pragma unroll
  for (int i = 0; i < 2; i++)
#pragma unroll
    for (int j = 0; j < 3; j++) acc[i][j] = (floatx4){0.f, 0.f, 0.f, 0.f};

  for (int k0 = 0; k0 < 256; k0 += 32) {
    load_lds16(qhb + k0, lAhi + tid * 8);
    load_lds16(qlb + k0, lAlo + tid * 8);
    load_lds16(Bhi + (size_t)bn * 512 + kbase + k0 + bc, lBhi + tid * 8);
    load_lds16(Blo + (size_t)bn * 512 + kbase + k0 + bc, lBlo + tid * 8);
    if (tid < 128) {   // waves 0,1 fully active (wave-uniform predicate)
      load_lds16(Bhi + (size_t)bn2 * 512 + kbase + k0 + bc2, lBhi + e2 * 8);
      load_lds16(Blo + (size_t)bn2 * 512 + kbase + k0 + bc2, lBlo + e2 * 8);
    }
    __syncthreads();

    short8 ah[2], al[2], bh[3], bl[3];
#pragma unroll
    for (int mi = 0; mi < 2; mi++) {
      int r = (wm * 32 + mi * 16 + lrow) * 32 + quad * 8;
      ah[mi] = *(const short8*)&lAhi[r];
      al[mi] = *(const short8*)&lAlo[r];
    }
#pragma unroll
    for (int ni = 0; ni < 3; ni++) {
      int r = (wn * 48 + ni * 16 + lrow) * 32 + quad * 8;
      bh[ni] = *(const short8*)&lBhi[r];
      bl[ni] = *(const short8*)&lBlo[r];
    }
#pragma unroll
    for (int mi = 0; mi < 2; mi++)
#pragma unroll
      for (int ni = 0; ni < 3; ni++) {
        acc[mi][ni] = __builtin_amdgcn_mfma_f32_16x16x32_bf16(ah[mi], bh[ni], acc[mi][ni], 0, 0, 0);
        acc[mi][ni] = __builtin_amdgcn_mfma_f32_16x16x32_bf16(ah[mi], bl[ni], acc[mi][ni], 0, 0, 0);
        acc[mi][ni] = __builtin_amdgcn_mfma_f32_16x16x32_bf16(al[mi], bh[ni], acc[mi][ni], 0, 0, 0);
      }
    __syncthreads();
  }

  float* out = P + (size_t)khalf * PSZF;
#pragma unroll
  for (int ni = 0; ni < 3; ni++) {
    int col = wn * 48 + ni * 16 + lrow;
    float bv = (khalf == 0) ? bcat[col] : 0.0f;
#pragma unroll
    for (int mi = 0; mi < 2; mi++) {
      int row = row0 + wm * 32 + mi * 16 + quad * 4;
#pragma unroll
      for (int r = 0; r < 4; r++)
        out[(size_t)(row + r) * 96 + col] = acc[mi][ni][r] + bv;
    }
  }
}

// ---------------- fused softmax + 1-D grid-sample gather ----------------
// One block per (b,l) row.  iy0 == 0 always (iy in [0,0.5]) so ywt = 1 - 0.5*loc_y.
// i0 in [1023,2047] always valid; i1 masked when == 2048.
// Gather phase: thread t covers head t>>5, channels 2*(t&31), 2*(t&31)+1 (uint loads).
__global__ __launch_bounds__(256) void sample_kernel(const float* __restrict__ P,
                                                     const unsigned short* __restrict__ v,
                                                     unsigned short* __restrict__ attn) {
  int row = blockIdx.x;
  int b = row >> 11, l = row & 2047;
  __shared__ float s_w0[32], s_w1[32];
  __shared__ int s_i0[32], s_i1[32];
  int tid = threadIdx.x;

  if (tid < 32) {                 // one thread per (h,p)
    int base = row * 96;
    float lg = P[base + 64 + tid] + P[PSZF + base + 64 + tid];
    float mx = fmaxf(lg, __shfl_xor(lg, 1));
    mx = fmaxf(mx, __shfl_xor(mx, 2));
    float e = __expf(lg - mx);
    float s = e + __shfl_xor(e, 1);
    s = s + __shfl_xor(s, 2);
    float aw = e / s;

    float ox = P[base + 2 * tid] + P[PSZF + base + 2 * tid];
    float oy = P[base + 2 * tid + 1] + P[PSZF + base + 2 * tid + 1];
    float refy = (float)l * (1.0f / 2047.0f);
    float lx = fminf(fmaxf(ox, 0.0f), 1.0f);
    float ly = fminf(fmaxf(oy + refy, 0.0f), 1.0f);
    float ix = ((lx + 1.0f) * 2048.0f - 1.0f) * 0.5f;
    float ywt = 1.0f - ly * 0.5f;
    float ix0 = floorf(ix);
    float fx = ix - ix0;
    int i0 = (int)ix0;
    int i1 = i0 + 1;
    s_w0[tid] = aw * ywt * (1.0f - fx);
    s_w1[tid] = (i1 < 2048) ? (aw * ywt * fx) : 0.0f;
    s_i0[tid] = i0;
    s_i1[tid] = (i1 < 2048) ? i1 : 2047;
  }
  __syncthreads();

  const unsigned short* vb = v + ((size_t)(b << 11)) * 512;
  int h = tid >> 5, c = (tid & 31) << 1;
  const unsigned short* vhc = vb + h * 64 + c;
  float ax = 0.0f, ay = 0.0f;
#pragma unroll
  for (int p = 0; p < 4; p++) {
    int t = (h << 2) + p;
    unsigned g0 = *(const unsigned*)(vhc + ((size_t)s_i0[t] << 9));
    unsigned g1 = *(const unsigned*)(vhc + ((size_t)s_i1[t] << 9));
    float w0 = s_w0[t], w1 = s_w1[t];
    ax += w0 * bf2f((unsigned short)g0) + w1 * bf2f((unsigned short)g1);
    ay += w0 * bf2f((unsigned short)(g0 >> 16)) + w1 * bf2f((unsigned short)(g1 >> 16));
  }
  unsigned packed = (unsigned)f2bf(ax) | ((unsigned)f2bf(ay) << 16);
  *(unsigned*)(attn + (size_t)row * 512 + h * 64 + c) = packed;
}

// ---------------- host launcher ----------------
extern "C" void kernel_launch(void* const* d_in, const int* in_sizes, int n_in,
                              void* d_out, int out_size, void* d_ws, size_t ws_size,
                              hipStream_t stream) {
  (void)in_sizes; (void)n_in; (void)out_size; (void)ws_size;
  const float* query = (const float*)d_in[0];
  // d_in[1] = key_in : unused by the reference
  const float* value = (const float*)d_in[2];
  const float* W_v   = (const float*)d_in[3];
  const float* b_v   = (const float*)d_in[4];
  const float* W_off = (const float*)d_in[5];
  const float* b_off = (const float*)d_in[6];
  const float* W_aw  = (const float*)d_in[7];
  const float* b_aw  = (const float*)d_in[8];
  const float* W_out = (const float*)d_in[9];
  const float* b_out = (const float*)d_in[10];
  float* out = (float*)d_out;

  char* ws = (char*)d_ws;
  const size_t MB = 1ull << 20;
  unsigned short* val_bf = (unsigned short*)(ws);                  // 16 MB (value bf16)
  unsigned short* attn   = val_bf;                                 // aliases: value dead after gemm1
  unsigned short* v_bf   = (unsigned short*)(ws + 16 * MB);        // 16 MB (v projection, bf16)
  unsigned short* Qhi    = (unsigned short*)(ws + 32 * MB);        // 16 MB
  unsigned short* Qlo    = (unsigned short*)(ws + 48 * MB);        // 16 MB
  float* offP            = (float*)(ws + 64 * MB);                 // 2 x 6 MB offaw partials
  unsigned short* Wv_t   = (unsigned short*)(ws + 80 * MB);        // 0.5 MB
  unsigned short* Wo_t   = (unsigned short*)(ws + 80 * MB + 524288);
  unsigned short* Bhi    = (unsigned short*)(ws + 81 * MB);        // 96 KB
  unsigned short* Blo    = (unsigned short*)(ws + 81 * MB + 98304);
  float* bcat            = (float*)(ws + 81 * MB + 196608);

  conv_all<<<16384, 256, 0, stream>>>(value, query, val_bf, Qhi, Qlo);
  prep_w<<<2241, 256, 0, stream>>>(W_v, W_out, W_off, W_aw, b_off, b_aw,
                                   Wv_t, Wo_t, Bhi, Blo, bcat);

  // v = value @ W_v + b_v   (bf16 out)
  gemm_bt<unsigned short><<<dim3(4, 128), 256, 0, stream>>>(val_bf, Wv_t, b_v, v_bf, 512, 512);
  // off/aw = query @ [W_off|W_aw] via split-bf16 3-product MFMA, split-K=2
  offaw2<<<dim3(2, 256), 256, 0, stream>>>(Qhi, Qlo, Bhi, Blo, bcat, offP);
  // softmax + grid-sample gather -> attn (bf16)
  sample_kernel<<<16384, 256, 0, stream>>>(offP, v_bf, attn);
  // out = attn @ W_out + b_out   (fp32 out)
  gemm_bt<float><<<dim3(4, 128), 256, 0, stream>>>(attn, Wo_t, b_out, out, 512, 512);
}

// Round 4
// 206.773 us; speedup vs baseline: 1.1259x; 1.0540x over previous
//
#include <hip/hip_runtime.h>
#include <stdint.h>

// Problem: B=8, L=2048, D=512, H=8, P=4, C=64.  M = B*L = 16384.
#define PSZF (16384 * 96)   // elements per offaw partial buffer (split-K half)

using short8  = __attribute__((ext_vector_type(8))) short;
using floatx4 = __attribute__((ext_vector_type(4))) float;

__device__ __forceinline__ unsigned short f2bf(float f) {  // RNE
  union { float f; unsigned u; } v; v.f = f;
  unsigned r = v.u + 0x7fffu + ((v.u >> 16) & 1u);
  return (unsigned short)(r >> 16);
}
__device__ __forceinline__ float bf2f(unsigned short u) {
  union { unsigned u; float f; } v; v.u = ((unsigned)u) << 16; return v.f;
}

__device__ __forceinline__ void load_lds16(const void* g, void* l) {
  __builtin_amdgcn_global_load_lds(
      (const __attribute__((address_space(1))) unsigned int*)g,
      (__attribute__((address_space(3))) unsigned int*)l, 16, 0, 0);
}

__device__ __forceinline__ void store_val(float* p, float v) { *p = v; }
__device__ __forceinline__ void store_val(unsigned short* p, float v) { *p = f2bf(v); }

// ---------------- K1: all conversions / weight prep in one launch ----------------
// [0, 2097152)          : value float4 -> bf16 ushort4
// [.., +262144)         : W_v^T bf16
// [.., +262144)         : W_out^T bf16
// [.., +49152)          : Bhi/Blo split-bf16 of [W_off|W_aw]^T  (layout [96][512])
// [.., +96)             : bcat
__global__ __launch_bounds__(256) void prep_all(const float* __restrict__ value,
                                                const float* __restrict__ W_v,
                                                const float* __restrict__ W_out,
                                                const float* __restrict__ Woff,
                                                const float* __restrict__ Waw,
                                                const float* __restrict__ boff,
                                                const float* __restrict__ baw,
                                                unsigned short* __restrict__ val_bf,
                                                unsigned short* __restrict__ Wv_t,
                                                unsigned short* __restrict__ Wo_t,
                                                unsigned short* __restrict__ Bhi,
                                                unsigned short* __restrict__ Blo,
                                                float* __restrict__ bcat) {
  int idx = blockIdx.x * 256 + threadIdx.x;
  if (idx < 2097152) {
    float4 v = ((const float4*)value)[idx];
    ushort4 o;
    o.x = f2bf(v.x); o.y = f2bf(v.y); o.z = f2bf(v.z); o.w = f2bf(v.w);
    ((ushort4*)val_bf)[idx] = o;
    return;
  }
  int t = idx - 2097152;
  if (t < 262144) {
    int n = t >> 9, k = t & 511;
    Wv_t[t] = f2bf(W_v[(k << 9) + n]);
    return;
  }
  t -= 262144;
  if (t < 262144) {
    int n = t >> 9, k = t & 511;
    Wo_t[t] = f2bf(W_out[(k << 9) + n]);
    return;
  }
  t -= 262144;
  if (t < 49152) {
    int n = t >> 9, k = t & 511;
    float w = (n < 64) ? Woff[(k << 6) + n] : Waw[(k << 5) + (n - 64)];
    unsigned short hi = f2bf(w);
    Bhi[t] = hi;
    Blo[t] = f2bf(w - bf2f(hi));
    return;
  }
  t -= 49152;
  if (t < 96) bcat[t] = (t < 64) ? boff[t] : baw[t - 64];
}

// ---------------- bf16 MFMA GEMM body (m97 structure, unchanged math) ----------------
// 128x128 tile, BK=32, 4 waves as 2x2 of 64x64, 16x16x32 MFMA, global_load_lds w=16.
template <typename OutT>
__device__ __forceinline__ void gemm_body(unsigned char* smem,
                                          const unsigned short* __restrict__ A,
                                          const unsigned short* __restrict__ Bt,
                                          const float* __restrict__ bias,
                                          OutT* __restrict__ C, int N, int K,
                                          int bx, int by) {
  unsigned short* lA = (unsigned short*)smem;           // 128*32 bf16 = 8 KB
  unsigned short* lB = (unsigned short*)(smem + 8192);  // 8 KB
  int tid  = threadIdx.x;
  int lane = tid & 63, wv = tid >> 6;
  int wm = wv & 1, wn = wv >> 1;
  int lrow = lane & 15, quad = lane >> 4;
  int rowBlk = by * 128, colBlk = bx * 128;

  const unsigned short* Ab = A + (size_t)rowBlk * K;
  const unsigned short* Bb = Bt + (size_t)colBlk * K;
  int r0 = tid >> 2;            // 0..63
  int c0 = (tid & 3) << 3;      // 0,8,16,24

  floatx4 acc[4][4];
#pragma unroll
  for (int i = 0; i < 4; i++)
#pragma unroll
    for (int j = 0; j < 4; j++) acc[i][j] = (floatx4){0.f, 0.f, 0.f, 0.f};

  for (int k0 = 0; k0 < K; k0 += 32) {
    load_lds16(Ab + (size_t)r0 * K + k0 + c0,        lA + tid * 8);
    load_lds16(Ab + (size_t)(r0 + 64) * K + k0 + c0, lA + 2048 + tid * 8);
    load_lds16(Bb + (size_t)r0 * K + k0 + c0,        lB + tid * 8);
    load_lds16(Bb + (size_t)(r0 + 64) * K + k0 + c0, lB + 2048 + tid * 8);
    __syncthreads();

    short8 a[4], b[4];
#pragma unroll
    for (int mi = 0; mi < 4; mi++)
      a[mi] = *(const short8*)&lA[(wm * 64 + mi * 16 + lrow) * 32 + quad * 8];
#pragma unroll
    for (int ni = 0; ni < 4; ni++)
      b[ni] = *(const short8*)&lB[(wn * 64 + ni * 16 + lrow) * 32 + quad * 8];
#pragma unroll
    for (int mi = 0; mi < 4; mi++)
#pragma unroll
      for (int ni = 0; ni < 4; ni++)
        acc[mi][ni] = __builtin_amdgcn_mfma_f32_16x16x32_bf16(a[mi], b[ni], acc[mi][ni], 0, 0, 0);
    __syncthreads();
  }

  // C/D layout: col = lane&15, row = quad*4 + reg   [verified m89/m91]
#pragma unroll
  for (int ni = 0; ni < 4; ni++) {
    int col = colBlk + wn * 64 + ni * 16 + lrow;
    float bv = bias[col];
#pragma unroll
    for (int mi = 0; mi < 4; mi++) {
      int row = rowBlk + wm * 64 + mi * 16 + quad * 4;
#pragma unroll
      for (int r = 0; r < 4; r++)
        store_val(&C[(size_t)(row + r) * N + col], acc[mi][ni][r] + bv);
    }
  }
}

// ---------------- offaw body: split-bf16 3-product MFMA, fp32 A read in-kernel ----
// P[khalf] = Qhi@Bhi + Qhi@Blo + Qlo@Bhi over 256 K (one accumulator).
// A: fp32 query read once, RNE-hi + trunc-lo residual split in registers -> LDS.
// B: global_load_lds (12 wave-chunks of 64 lanes x 16 B across hi+lo).
// 64x96 tile, 4 waves as 2x2 of 32x48.  bid in [0,512): khalf = bid>>8.
__device__ __forceinline__ void offaw_body(unsigned char* smem,
                                           const float* __restrict__ Q,
                                           const unsigned short* __restrict__ Bhi,
                                           const unsigned short* __restrict__ Blo,
                                           const float* __restrict__ bcat,
                                           float* __restrict__ P, int bid) {
  unsigned short* lAhi = (unsigned short*)smem;            // 64*32 = 4 KB
  unsigned short* lAlo = (unsigned short*)(smem + 4096);   // 4 KB
  unsigned short* lBhi = (unsigned short*)(smem + 8192);   // 96*32 = 6 KB
  unsigned short* lBlo = (unsigned short*)(smem + 14336);  // 6 KB
  int khalf = bid >> 8, row0 = (bid & 255) * 64, kbase = khalf << 8;
  int tid = threadIdx.x, lane = tid & 63, wv = tid >> 6;
  int wm = wv & 1, wn = wv >> 1, lrow = lane & 15, quad = lane >> 4;

  int ar = tid >> 2, ac = (tid & 3) << 3;   // A row 0..63, col {0,8,16,24}
  const float* qp = Q + (size_t)(row0 + ar) * 512 + kbase + ac;

  floatx4 acc[2][3];
#pragma unroll
  for (int i = 0; i < 2; i++)
#pragma unroll
    for (int j = 0; j < 3; j++) acc[i][j] = (floatx4){0.f, 0.f, 0.f, 0.f};

  for (int k0 = 0; k0 < 256; k0 += 32) {
    // --- stage A: 8 fp32 -> (hi RNE, lo = trunc residual); exactly compensated ---
    float4 v0 = *(const float4*)(qp + k0);
    float4 v1 = *(const float4*)(qp + k0 + 4);
    float vv[8] = {v0.x, v0.y, v0.z, v0.w, v1.x, v1.y, v1.z, v1.w};
    short8 h8, l8;
#pragma unroll
    for (int e = 0; e < 8; e++) {
      union { float f; unsigned u; } t; t.f = vv[e];
      unsigned r = t.u + 0x7fffu + ((t.u >> 16) & 1u);
      h8[e] = (short)(r >> 16);
      union { unsigned u; float f; } hf; hf.u = r & 0xffff0000u;
      union { float f; unsigned u; } rb; rb.f = vv[e] - hf.f;
      l8[e] = (short)(rb.u >> 16);
    }
    *(short8*)&lAhi[tid * 8] = h8;
    *(short8*)&lAlo[tid * 8] = l8;
    // --- stage B: 2 x 384 16B-chunks; wave-uniform buffer per chunk-group ---
#pragma unroll
    for (int j = 0; j < 3; j++) {
      int widx = wv + (j << 2);                        // 0..11, wave-uniform
      const unsigned short* src = (widx < 6) ? Bhi : Blo;
      unsigned short* dst = (widx < 6) ? lBhi : lBlo;
      int c = (((widx < 6) ? widx : widx - 6) << 6) + lane;  // 0..383
      int n = c >> 2, cc = (c & 3) << 3;
      load_lds16(src + (size_t)n * 512 + kbase + k0 + cc, dst + c * 8);
    }
    __syncthreads();

    short8 ah[2], al[2], bh[3], bl[3];
#pragma unroll
    for (int mi = 0; mi < 2; mi++) {
      int r = (wm * 32 + mi * 16 + lrow) * 32 + quad * 8;
      ah[mi] = *(const short8*)&lAhi[r];
      al[mi] = *(const short8*)&lAlo[r];
    }
#pragma unroll
    for (int ni = 0; ni < 3; ni++) {
      int r = (wn * 48 + ni * 16 + lrow) * 32 + quad * 8;
      bh[ni] = *(const short8*)&lBhi[r];
      bl[ni] = *(const short8*)&lBlo[r];
    }
#pragma unroll
    for (int mi = 0; mi < 2; mi++)
#pragma unroll
      for (int ni = 0; ni < 3; ni++) {
        acc[mi][ni] = __builtin_amdgcn_mfma_f32_16x16x32_bf16(ah[mi], bh[ni], acc[mi][ni], 0, 0, 0);
        acc[mi][ni] = __builtin_amdgcn_mfma_f32_16x16x32_bf16(ah[mi], bl[ni], acc[mi][ni], 0, 0, 0);
        acc[mi][ni] = __builtin_amdgcn_mfma_f32_16x16x32_bf16(al[mi], bh[ni], acc[mi][ni], 0, 0, 0);
      }
    __syncthreads();
  }

  float* out = P + (size_t)khalf * PSZF;
#pragma unroll
  for (int ni = 0; ni < 3; ni++) {
    int col = wn * 48 + ni * 16 + lrow;
    float bv = (khalf == 0) ? bcat[col] : 0.0f;
#pragma unroll
    for (int mi = 0; mi < 2; mi++) {
      int row = row0 + wm * 32 + mi * 16 + quad * 4;
#pragma unroll
      for (int r = 0; r < 4; r++)
        out[(size_t)(row + r) * 96 + col] = acc[mi][ni][r] + bv;
    }
  }
}

// ---------------- K2: gemm1 + offaw fused via grid split (independent work) ----------
__global__ __launch_bounds__(256) void mega_k2(const unsigned short* __restrict__ val_bf,
                                               const unsigned short* __restrict__ Wv_t,
                                               const float* __restrict__ b_v,
                                               unsigned short* __restrict__ v_bf,
                                               const float* __restrict__ query,
                                               const unsigned short* __restrict__ Bhi,
                                               const unsigned short* __restrict__ Blo,
                                               const float* __restrict__ bcat,
                                               float* __restrict__ offP) {
  __shared__ __align__(16) unsigned char smem[20480];   // gemm uses 16K, offaw 20K
  int bx = blockIdx.x;
  if (bx < 512)
    gemm_body<unsigned short>(smem, val_bf, Wv_t, b_v, v_bf, 512, 512, bx & 3, bx >> 2);
  else
    offaw_body(smem, query, Bhi, Blo, bcat, offP, bx - 512);
}

// ---------------- K4: out = attn @ W_out + b_out ----------------
__global__ __launch_bounds__(256) void gemm2_k(const unsigned short* __restrict__ A,
                                               const unsigned short* __restrict__ Bt,
                                               const float* __restrict__ bias,
                                               float* __restrict__ C) {
  __shared__ __align__(16) unsigned char smem[16384];
  gemm_body<float>(smem, A, Bt, bias, C, 512, 512, blockIdx.x & 3, blockIdx.x >> 2);
}

// ---------------- K3: fused softmax + 1-D grid-sample gather ----------------
// One block per (b,l) row.  iy0 == 0 always (iy in [0,0.5]) so ywt = 1 - 0.5*loc_y.
// Gather: thread t covers head t>>5, channels 2*(t&31), 2*(t&31)+1 (uint loads).
__global__ __launch_bounds__(256) void sample_kernel(const float* __restrict__ P,
                                                     const unsigned short* __restrict__ v,
                                                     unsigned short* __restrict__ attn) {
  int row = blockIdx.x;
  int b = row >> 11, l = row & 2047;
  __shared__ float s_w0[32], s_w1[32];
  __shared__ int s_i0[32], s_i1[32];
  int tid = threadIdx.x;

  if (tid < 32) {                 // one thread per (h,p)
    int base = row * 96;
    float lg = P[base + 64 + tid] + P[PSZF + base + 64 + tid];
    float mx = fmaxf(lg, __shfl_xor(lg, 1));
    mx = fmaxf(mx, __shfl_xor(mx, 2));
    float e = __expf(lg - mx);
    float s = e + __shfl_xor(e, 1);
    s = s + __shfl_xor(s, 2);
    float aw = e / s;

    float ox = P[base + 2 * tid] + P[PSZF + base + 2 * tid];
    float oy = P[base + 2 * tid + 1] + P[PSZF + base + 2 * tid + 1];
    float refy = (float)l * (1.0f / 2047.0f);
    float lx = fminf(fmaxf(ox, 0.0f), 1.0f);
    float ly = fminf(fmaxf(oy + refy, 0.0f), 1.0f);
    float ix = ((lx + 1.0f) * 2048.0f - 1.0f) * 0.5f;
    float ywt = 1.0f - ly * 0.5f;
    float ix0 = floorf(ix);
    float fx = ix - ix0;
    int i0 = (int)ix0;
    int i1 = i0 + 1;
    s_w0[tid] = aw * ywt * (1.0f - fx);
    s_w1[tid] = (i1 < 2048) ? (aw * ywt * fx) : 0.0f;
    s_i0[tid] = i0;
    s_i1[tid] = (i1 < 2048) ? i1 : 2047;
  }
  __syncthreads();

  const unsigned short* vb = v + ((size_t)(b << 11)) * 512;
  int h = tid >> 5, c = (tid & 31) << 1;
  const unsigned short* vhc = vb + h * 64 + c;
  float ax = 0.0f, ay = 0.0f;
#pragma unroll
  for (int p = 0; p < 4; p++) {
    int t = (h << 2) + p;
    unsigned g0 = *(const unsigned*)(vhc + ((size_t)s_i0[t] << 9));
    unsigned g1 = *(const unsigned*)(vhc + ((size_t)s_i1[t] << 9));
    float w0 = s_w0[t], w1 = s_w1[t];
    ax += w0 * bf2f((unsigned short)g0) + w1 * bf2f((unsigned short)g1);
    ay += w0 * bf2f((unsigned short)(g0 >> 16)) + w1 * bf2f((unsigned short)(g1 >> 16));
  }
  unsigned packed = (unsigned)f2bf(ax) | ((unsigned)f2bf(ay) << 16);
  *(unsigned*)(attn + (size_t)row * 512 + h * 64 + c) = packed;
}

// ---------------- host launcher ----------------
extern "C" void kernel_launch(void* const* d_in, const int* in_sizes, int n_in,
                              void* d_out, int out_size, void* d_ws, size_t ws_size,
                              hipStream_t stream) {
  (void)in_sizes; (void)n_in; (void)out_size; (void)ws_size;
  const float* query = (const float*)d_in[0];
  // d_in[1] = key_in : unused by the reference
  const float* value = (const float*)d_in[2];
  const float* W_v   = (const float*)d_in[3];
  const float* b_v   = (const float*)d_in[4];
  const float* W_off = (const float*)d_in[5];
  const float* b_off = (const float*)d_in[6];
  const float* W_aw  = (const float*)d_in[7];
  const float* b_aw  = (const float*)d_in[8];
  const float* W_out = (const float*)d_in[9];
  const float* b_out = (const float*)d_in[10];
  float* out = (float*)d_out;

  char* ws = (char*)d_ws;
  const size_t MB = 1ull << 20;
  unsigned short* val_bf = (unsigned short*)(ws);                  // 16 MB (value bf16)
  unsigned short* attn   = val_bf;                                 // alias: value dead after K2
  unsigned short* v_bf   = (unsigned short*)(ws + 16 * MB);        // 16 MB (v projection, bf16)
  float* offP            = (float*)(ws + 32 * MB);                 // 2 x 6 MB offaw partials
  unsigned short* Wv_t   = (unsigned short*)(ws + 48 * MB);        // 0.5 MB
  unsigned short* Wo_t   = (unsigned short*)(ws + 48 * MB + 524288);
  unsigned short* Bhi    = (unsigned short*)(ws + 49 * MB);        // 96 KB
  unsigned short* Blo    = (unsigned short*)(ws + 49 * MB + 98304);
  float* bcat            = (float*)(ws + 49 * MB + 196608);

  // K1: all conversions + weight prep
  prep_all<<<10433, 256, 0, stream>>>(value, W_v, W_out, W_off, W_aw, b_off, b_aw,
                                      val_bf, Wv_t, Wo_t, Bhi, Blo, bcat);
  // K2: v = value@W_v + b_v (bf16 out)  ||  offaw = query@[W_off|W_aw] split-bf16
  mega_k2<<<1024, 256, 0, stream>>>(val_bf, Wv_t, b_v, v_bf, query, Bhi, Blo, bcat, offP);
  // K3: softmax + grid-sample gather -> attn (bf16)
  sample_kernel<<<16384, 256, 0, stream>>>(offP, v_bf, attn);
  // K4: out = attn @ W_out + b_out (fp32 out)
  gemm2_k<<<512, 256, 0, stream>>>(attn, Wo_t, b_out, out);
}